// Round 1
// baseline (485.565 us; speedup 1.0000x reference)
//
#include <hip/hip_runtime.h>
#include <hip/hip_bf16.h>
#include <math.h>

#define EPS 1e-5f

// ---------------------------------------------------------------------------
// GEMM + BN: out[b,o,n] = BN_o( sum_c w[o,c] * x[b,c,n] )
// x: (B, 256, 1024), w: (CO, 256), out: (B, CO, 1024)
// 64x64 output tile per block, 256 threads, 4x4 micro-tile per thread.
// ---------------------------------------------------------------------------
template<int CO>
__global__ __launch_bounds__(256)
void gemm_bn_kernel(const float* __restrict__ x, const float* __restrict__ w,
                    const float* __restrict__ g, const float* __restrict__ bbias,
                    const float* __restrict__ bmean, const float* __restrict__ bvar,
                    float* __restrict__ out)
{
    const int b  = blockIdx.z;
    const int o0 = blockIdx.y * 64;
    const int n0 = blockIdx.x * 64;
    const float* xb = x + (size_t)b * 256 * 1024;

    __shared__ float wt[64][36];   // [o][k], padded row stride 36 (16B-aligned, conflict-light)
    __shared__ float xt[32][64];   // [k][n]

    const int tid = threadIdx.x;
    const int tx = tid & 15, ty = tid >> 4;

    float acc[4][4] = {};

    for (int k0 = 0; k0 < 256; k0 += 32) {
        __syncthreads();
        // stage W tile: 64 rows x 32 k -> 2048 floats, 2 float4 per thread
        #pragma unroll
        for (int i = 0; i < 2; i++) {
            int e = (tid + i * 256) * 4;
            int r = e >> 5, c = e & 31;
            *(float4*)&wt[r][c] = *(const float4*)&w[(size_t)(o0 + r) * 256 + k0 + c];
        }
        // stage X tile: 32 k x 64 n -> 2048 floats
        #pragma unroll
        for (int i = 0; i < 2; i++) {
            int e = (tid + i * 256) * 4;
            int r = e >> 6, c = e & 63;
            *(float4*)&xt[r][c] = *(const float4*)&xb[(size_t)(k0 + r) * 1024 + n0 + c];
        }
        __syncthreads();
        #pragma unroll
        for (int kk = 0; kk < 32; kk++) {
            float4 bv = *(float4*)&xt[kk][tx * 4];
            float a0 = wt[ty * 4 + 0][kk];
            float a1 = wt[ty * 4 + 1][kk];
            float a2 = wt[ty * 4 + 2][kk];
            float a3 = wt[ty * 4 + 3][kk];
            acc[0][0] += a0 * bv.x; acc[0][1] += a0 * bv.y; acc[0][2] += a0 * bv.z; acc[0][3] += a0 * bv.w;
            acc[1][0] += a1 * bv.x; acc[1][1] += a1 * bv.y; acc[1][2] += a1 * bv.z; acc[1][3] += a1 * bv.w;
            acc[2][0] += a2 * bv.x; acc[2][1] += a2 * bv.y; acc[2][2] += a2 * bv.z; acc[2][3] += a2 * bv.w;
            acc[3][0] += a3 * bv.x; acc[3][1] += a3 * bv.y; acc[3][2] += a3 * bv.z; acc[3][3] += a3 * bv.w;
        }
    }

    #pragma unroll
    for (int i = 0; i < 4; i++) {
        int o = o0 + ty * 4 + i;
        float s  = g[o] * rsqrtf(bvar[o] + EPS);
        float sh = bbias[o] - bmean[o] * s;
        float4 r;
        r.x = acc[i][0] * s + sh;
        r.y = acc[i][1] * s + sh;
        r.z = acc[i][2] * s + sh;
        r.w = acc[i][3] * s + sh;
        *(float4*)&out[((size_t)b * CO + o) * 1024 + n0 + tx * 4] = r;
    }
}

// ---------------------------------------------------------------------------
// Depthwise 3x3 conv (SAME, groups=C) on v + BN -> WRITES y.
// v lives in qkv workspace: channel (h*32+c) is qkv channel (h*64+32+c).
// One block per (b, ch); 32x32 plane staged in LDS.
// ---------------------------------------------------------------------------
__global__ __launch_bounds__(256)
void pe_conv_bn_kernel(const float* __restrict__ qkv, const float* __restrict__ wpe,
                       const float* __restrict__ g, const float* __restrict__ bbias,
                       const float* __restrict__ bmean, const float* __restrict__ bvar,
                       float* __restrict__ y)
{
    const int bc = blockIdx.x;
    const int b = bc >> 8, ch = bc & 255;
    const int h = ch >> 5, c = ch & 31;
    const float* vp = qkv + ((size_t)b * 512 + h * 64 + 32 + c) * 1024;

    __shared__ float plane[1024];
    const int tid = threadIdx.x;
    *(float4*)&plane[tid * 4] = *(const float4*)&vp[tid * 4];

    float wk[9];
    #pragma unroll
    for (int i = 0; i < 9; i++) wk[i] = wpe[ch * 9 + i];
    float s  = g[ch] * rsqrtf(bvar[ch] + EPS);
    float sh = bbias[ch] - bmean[ch] * s;
    __syncthreads();

    float* yp = y + ((size_t)b * 256 + ch) * 1024;
    #pragma unroll
    for (int it = 0; it < 4; it++) {
        int p = tid + it * 256;
        int py = p >> 5, px = p & 31;
        float a = 0.f;
        #pragma unroll
        for (int dy = -1; dy <= 1; dy++) {
            int yy = py + dy;
            if (yy < 0 || yy > 31) continue;
            #pragma unroll
            for (int dx = -1; dx <= 1; dx++) {
                int xx = px + dx;
                if (xx < 0 || xx > 31) continue;
                a += plane[yy * 32 + xx] * wk[(dy + 1) * 3 + (dx + 1)];
            }
        }
        yp[p] = a * s + sh;
    }
}

// ---------------------------------------------------------------------------
// Attention: per (b,h): S = (Q^T K) * 0.25, softmax over keys, out = V attn^T.
// One thread per query n; online softmax over 32-key tiles staged in LDS.
// ADDS into y (pe already written there).
// ---------------------------------------------------------------------------
__global__ __launch_bounds__(128)
void attn_kernel(const float* __restrict__ qkv, float* __restrict__ y)
{
    const int bh = blockIdx.y;
    const int b = bh >> 3, h = bh & 7;
    const float* base = qkv + ((size_t)b * 512 + h * 64) * 1024;
    const int tid = threadIdx.x;
    const int n = blockIdx.x * 128 + tid;

    float q[16];
    #pragma unroll
    for (int c = 0; c < 16; c++) q[c] = base[(size_t)c * 1024 + n] * 0.25f;

    __shared__ float k_lds[16][32];
    __shared__ float v_lds[32][32];

    float acc[32];
    #pragma unroll
    for (int c = 0; c < 32; c++) acc[c] = 0.f;
    float mrun = -1e30f, lrun = 0.f;

    for (int m0 = 0; m0 < 1024; m0 += 32) {
        __syncthreads();
        {
            // K tile: 16x32 = 512 floats; 128 threads x 1 float4
            int e = tid * 4;
            int r = e >> 5, cm = e & 31;
            *(float4*)&k_lds[r][cm] = *(const float4*)&base[(size_t)(16 + r) * 1024 + m0 + cm];
            // V tile: 32x32 = 1024 floats; 2 float4 per thread
            #pragma unroll
            for (int i = 0; i < 2; i++) {
                int e2 = (tid + i * 128) * 4;
                int r2 = e2 >> 5, cm2 = e2 & 31;
                *(float4*)&v_lds[r2][cm2] = *(const float4*)&base[(size_t)(32 + r2) * 1024 + m0 + cm2];
            }
        }
        __syncthreads();

        float s[32];
        #pragma unroll
        for (int mm = 0; mm < 32; mm += 4) {
            float s0 = 0.f, s1 = 0.f, s2 = 0.f, s3 = 0.f;
            #pragma unroll
            for (int c = 0; c < 16; c++) {
                float4 k4 = *(float4*)&k_lds[c][mm];
                s0 += q[c] * k4.x; s1 += q[c] * k4.y; s2 += q[c] * k4.z; s3 += q[c] * k4.w;
            }
            s[mm] = s0; s[mm + 1] = s1; s[mm + 2] = s2; s[mm + 3] = s3;
        }

        float tmax = mrun;
        #pragma unroll
        for (int mm = 0; mm < 32; mm++) tmax = fmaxf(tmax, s[mm]);
        float corr = __expf(mrun - tmax);
        mrun = tmax;
        lrun *= corr;
        #pragma unroll
        for (int c = 0; c < 32; c++) acc[c] *= corr;

        float psum = 0.f;
        #pragma unroll
        for (int mm = 0; mm < 32; mm++) {
            float p = __expf(s[mm] - tmax);
            s[mm] = p;
            psum += p;
        }
        lrun += psum;

        #pragma unroll
        for (int mm = 0; mm < 32; mm += 4) {
            float p0 = s[mm], p1 = s[mm + 1], p2 = s[mm + 2], p3 = s[mm + 3];
            #pragma unroll
            for (int c = 0; c < 32; c++) {
                float4 v4 = *(float4*)&v_lds[c][mm];
                acc[c] += p0 * v4.x;
                acc[c] += p1 * v4.y;
                acc[c] += p2 * v4.z;
                acc[c] += p3 * v4.w;
            }
        }
    }

    float inv = 1.f / lrun;
    float* yp = y + ((size_t)b * 256 + h * 32) * 1024 + n;
    #pragma unroll
    for (int c = 0; c < 32; c++) yp[(size_t)c * 1024] += acc[c] * inv;
}

// ---------------------------------------------------------------------------
extern "C" void kernel_launch(void* const* d_in, const int* in_sizes, int n_in,
                              void* d_out, int out_size, void* d_ws, size_t ws_size,
                              hipStream_t stream)
{
    const float* x      = (const float*)d_in[0];
    const float* w_qkv  = (const float*)d_in[1];
    const float* qkv_g  = (const float*)d_in[2];
    const float* qkv_b  = (const float*)d_in[3];
    const float* qkv_m  = (const float*)d_in[4];
    const float* qkv_v  = (const float*)d_in[5];
    const float* w_pe   = (const float*)d_in[6];
    const float* pe_g   = (const float*)d_in[7];
    const float* pe_b   = (const float*)d_in[8];
    const float* pe_m   = (const float*)d_in[9];
    const float* pe_v   = (const float*)d_in[10];
    const float* w_proj = (const float*)d_in[11];
    const float* proj_g = (const float*)d_in[12];
    const float* proj_b = (const float*)d_in[13];
    const float* proj_m = (const float*)d_in[14];
    const float* proj_v = (const float*)d_in[15];

    float* out = (float*)d_out;
    float* qkv = (float*)d_ws;                        // 8*512*1024 floats = 16 MB
    float* y   = qkv + (size_t)8 * 512 * 1024;        // 8*256*1024 floats =  8 MB

    // 1) QKV 1x1 conv + BN
    gemm_bn_kernel<512><<<dim3(16, 8, 8), 256, 0, stream>>>(
        x, w_qkv, qkv_g, qkv_b, qkv_m, qkv_v, qkv);

    // 2) depthwise 3x3 PE conv + BN (writes y)
    pe_conv_bn_kernel<<<dim3(2048), 256, 0, stream>>>(
        qkv, w_pe, pe_g, pe_b, pe_m, pe_v, y);

    // 3) attention (adds into y)
    attn_kernel<<<dim3(8, 64), 128, 0, stream>>>(qkv, y);

    // 4) proj 1x1 conv + BN -> output
    gemm_bn_kernel<256><<<dim3(16, 4, 8), 256, 0, stream>>>(
        y, w_proj, proj_g, proj_b, proj_m, proj_v, out);
}

// Round 2
// 100.328 us; speedup vs baseline: 4.8398x; 4.8398x over previous
//
#include <hip/hip_runtime.h>
#include <hip/hip_bf16.h>
#include <math.h>

#define EPS 1e-5f

typedef __attribute__((ext_vector_type(8))) short bf16x8;
typedef __attribute__((ext_vector_type(16))) float f32x16;

__device__ inline unsigned short f2bf(float x) {
    __hip_bfloat16 b = __float2bfloat16(x);
    return *reinterpret_cast<unsigned short*>(&b);
}

// ---------------------------------------------------------------------------
// GEMM + BN: out[b,o,n] = BN_o( sum_c w[o,c] * x[b,c,n] )  (unchanged from R1)
// ---------------------------------------------------------------------------
template<int CO>
__global__ __launch_bounds__(256)
void gemm_bn_kernel(const float* __restrict__ x, const float* __restrict__ w,
                    const float* __restrict__ g, const float* __restrict__ bbias,
                    const float* __restrict__ bmean, const float* __restrict__ bvar,
                    float* __restrict__ out)
{
    const int b  = blockIdx.z;
    const int o0 = blockIdx.y * 64;
    const int n0 = blockIdx.x * 64;
    const float* xb = x + (size_t)b * 256 * 1024;

    __shared__ float wt[64][36];
    __shared__ float xt[32][64];

    const int tid = threadIdx.x;
    const int tx = tid & 15, ty = tid >> 4;

    float acc[4][4] = {};

    for (int k0 = 0; k0 < 256; k0 += 32) {
        __syncthreads();
        #pragma unroll
        for (int i = 0; i < 2; i++) {
            int e = (tid + i * 256) * 4;
            int r = e >> 5, c = e & 31;
            *(float4*)&wt[r][c] = *(const float4*)&w[(size_t)(o0 + r) * 256 + k0 + c];
        }
        #pragma unroll
        for (int i = 0; i < 2; i++) {
            int e = (tid + i * 256) * 4;
            int r = e >> 6, c = e & 63;
            *(float4*)&xt[r][c] = *(const float4*)&xb[(size_t)(k0 + r) * 1024 + n0 + c];
        }
        __syncthreads();
        #pragma unroll
        for (int kk = 0; kk < 32; kk++) {
            float4 bv = *(float4*)&xt[kk][tx * 4];
            float a0 = wt[ty * 4 + 0][kk];
            float a1 = wt[ty * 4 + 1][kk];
            float a2 = wt[ty * 4 + 2][kk];
            float a3 = wt[ty * 4 + 3][kk];
            acc[0][0] += a0 * bv.x; acc[0][1] += a0 * bv.y; acc[0][2] += a0 * bv.z; acc[0][3] += a0 * bv.w;
            acc[1][0] += a1 * bv.x; acc[1][1] += a1 * bv.y; acc[1][2] += a1 * bv.z; acc[1][3] += a1 * bv.w;
            acc[2][0] += a2 * bv.x; acc[2][1] += a2 * bv.y; acc[2][2] += a2 * bv.z; acc[2][3] += a2 * bv.w;
            acc[3][0] += a3 * bv.x; acc[3][1] += a3 * bv.y; acc[3][2] += a3 * bv.z; acc[3][3] += a3 * bv.w;
        }
    }

    #pragma unroll
    for (int i = 0; i < 4; i++) {
        int o = o0 + ty * 4 + i;
        float s  = g[o] * rsqrtf(bvar[o] + EPS);
        float sh = bbias[o] - bmean[o] * s;
        float4 r;
        r.x = acc[i][0] * s + sh;
        r.y = acc[i][1] * s + sh;
        r.z = acc[i][2] * s + sh;
        r.w = acc[i][3] * s + sh;
        *(float4*)&out[((size_t)b * CO + o) * 1024 + n0 + tx * 4] = r;
    }
}

// ---------------------------------------------------------------------------
// Depthwise 3x3 conv + BN -> WRITES y.  (unchanged from R1)
// ---------------------------------------------------------------------------
__global__ __launch_bounds__(256)
void pe_conv_bn_kernel(const float* __restrict__ qkv, const float* __restrict__ wpe,
                       const float* __restrict__ g, const float* __restrict__ bbias,
                       const float* __restrict__ bmean, const float* __restrict__ bvar,
                       float* __restrict__ y)
{
    const int bc = blockIdx.x;
    const int b = bc >> 8, ch = bc & 255;
    const int h = ch >> 5, c = ch & 31;
    const float* vp = qkv + ((size_t)b * 512 + h * 64 + 32 + c) * 1024;

    __shared__ float plane[1024];
    const int tid = threadIdx.x;
    *(float4*)&plane[tid * 4] = *(const float4*)&vp[tid * 4];

    float wk[9];
    #pragma unroll
    for (int i = 0; i < 9; i++) wk[i] = wpe[ch * 9 + i];
    float s  = g[ch] * rsqrtf(bvar[ch] + EPS);
    float sh = bbias[ch] - bmean[ch] * s;
    __syncthreads();

    float* yp = y + ((size_t)b * 256 + ch) * 1024;
    #pragma unroll
    for (int it = 0; it < 4; it++) {
        int p = tid + it * 256;
        int py = p >> 5, px = p & 31;
        float a = 0.f;
        #pragma unroll
        for (int dy = -1; dy <= 1; dy++) {
            int yy = py + dy;
            if (yy < 0 || yy > 31) continue;
            #pragma unroll
            for (int dx = -1; dx <= 1; dx++) {
                int xx = px + dx;
                if (xx < 0 || xx > 31) continue;
                a += plane[yy * 32 + xx] * wk[(dy + 1) * 3 + (dx + 1)];
            }
        }
        yp[p] = a * s + sh;
    }
}

// ---------------------------------------------------------------------------
// Pre-pass: qkv fp32 [b][512][1024] -> QT/KT bf16 [bh][1024 n][16 c]
// (Q pre-scaled by 0.25). Block: 256 thr handles one (bh, 256-n slab).
// ---------------------------------------------------------------------------
__global__ __launch_bounds__(256)
void qk_transpose_kernel(const float* __restrict__ qkv,
                         unsigned short* __restrict__ qt,
                         unsigned short* __restrict__ kt)
{
    const int bh = blockIdx.y;
    const int n0 = blockIdx.x * 256;
    const int b = bh >> 3, h = bh & 7;
    const float* src = qkv + ((size_t)(b * 512 + h * 64)) * 1024 + n0;

    __shared__ float tile[32][260];   // 260 pad: 16B-aligned rows, conflict-free col reads
    const int tid = threadIdx.x;
    #pragma unroll
    for (int i = 0; i < 8; i++) {
        int e = (tid + i * 256) * 4;  // 8192 floats total
        int r = e >> 8, cn = e & 255;
        *(float4*)&tile[r][cn] = *(const float4*)(src + (size_t)r * 1024 + cn);
    }
    __syncthreads();

    {   // Q half (c=0..15), scaled
        unsigned int w[8];
        #pragma unroll
        for (int g = 0; g < 8; g++) {
            float a  = tile[2 * g][tid] * 0.25f;
            float bq = tile[2 * g + 1][tid] * 0.25f;
            w[g] = f2bf(a) | ((unsigned int)f2bf(bq) << 16);
        }
        unsigned short* dst = qt + ((size_t)bh * 1024 + n0 + tid) * 16;
        *(uint4*)dst = make_uint4(w[0], w[1], w[2], w[3]);
        *(uint4*)(dst + 8) = make_uint4(w[4], w[5], w[6], w[7]);
    }
    {   // K half (c=16..31)
        unsigned int w[8];
        #pragma unroll
        for (int g = 0; g < 8; g++) {
            float a  = tile[16 + 2 * g][tid];
            float bq = tile[16 + 2 * g + 1][tid];
            w[g] = f2bf(a) | ((unsigned int)f2bf(bq) << 16);
        }
        unsigned short* dst = kt + ((size_t)bh * 1024 + n0 + tid) * 16;
        *(uint4*)dst = make_uint4(w[0], w[1], w[2], w[3]);
        *(uint4*)(dst + 8) = make_uint4(w[4], w[5], w[6], w[7]);
    }
}

// ---------------------------------------------------------------------------
// MFMA flash attention. Block = 256 thr = 4 waves; wave w owns 32 queries.
// Per 32-key chunk: S^T = mfma(Kfrag, Qfrag); in-register online softmax
// (lane pair l / l^32 holds one query's 32 scores); P via per-wave LDS
// roundtrip; PV = 2x mfma(Vfrag, Pfrag). V staged fp32->bf16, double-buffered.
// ADDS into y.
// ---------------------------------------------------------------------------
__global__ __launch_bounds__(256)
void attn_mfma_kernel(const float* __restrict__ qkv,
                      const unsigned short* __restrict__ qt,
                      const unsigned short* __restrict__ kt,
                      float* __restrict__ y)
{
    const int bh = blockIdx.y;
    const int b = bh >> 3, h = bh & 7;
    const int tid = threadIdx.x;
    const int wid = tid >> 6;
    const int lane = tid & 63;
    const int col = lane & 31;      // query col (B/D), channel row (A of PV), key row (A of QK)
    const int h2 = lane >> 5;
    const int q0 = blockIdx.x * 128 + wid * 32;

    __shared__ unsigned short v_lds[2][32][40];  // 80B rows: 16B-aligned, ~4-way banks
    __shared__ unsigned short p_lds[4][32][40];  // per-wave P tile

    bf16x8 qf = *(const bf16x8*)(qt + ((size_t)bh * 1024 + q0 + col) * 16 + h2 * 8);
    const unsigned short* ktb = kt + (size_t)bh * 1024 * 16;
    const float* vsrc = qkv + ((size_t)(b * 512 + h * 64 + 32)) * 1024;

    const int sc = tid >> 3;        // staging: channel 0..31
    const int sm = (tid & 7) * 4;   // staging: m offset

    f32x16 acc = {};
    float mrun = -1e30f, lrun = 0.f;

    {   // stage chunk 0
        float4 v4 = *(const float4*)(vsrc + (size_t)sc * 1024 + sm);
        unsigned int w0 = f2bf(v4.x) | ((unsigned int)f2bf(v4.y) << 16);
        unsigned int w1 = f2bf(v4.z) | ((unsigned int)f2bf(v4.w) << 16);
        *(uint2*)&v_lds[0][sc][sm] = make_uint2(w0, w1);
    }
    __syncthreads();

    for (int j = 0; j < 32; j++) {
        const int m0 = j * 32;

        // prefetch next V chunk early (consumed at loop bottom)
        float4 nv;
        if (j < 31) nv = *(const float4*)(vsrc + (size_t)sc * 1024 + (m0 + 32) + sm);

        // S^T[m][n] = sum_c K[c][m]*Q[c][n]*0.25 : A = K-chunk^T, B = Q-tile
        bf16x8 kf = *(const bf16x8*)(ktb + (size_t)(m0 + col) * 16 + h2 * 8);
        f32x16 zero = {};
        f32x16 s = __builtin_amdgcn_mfma_f32_32x32x16_bf16(kf, qf, zero, 0, 0, 0);

        // online softmax: lane l (rows {0-3,8-11,16-19,24-27}+4*h2) + partner l^32
        float tmax = s[0];
        #pragma unroll
        for (int r = 1; r < 16; r++) tmax = fmaxf(tmax, s[r]);
        tmax = fmaxf(tmax, __shfl_xor(tmax, 32, 64));
        float mnew = fmaxf(mrun, tmax);
        float corr = __expf(mrun - mnew);

        float ps = 0.f;
        unsigned int pw[8];
        #pragma unroll
        for (int g = 0; g < 4; g++) {
            float p0 = __expf(s[4 * g + 0] - mnew);
            float p1 = __expf(s[4 * g + 1] - mnew);
            float p2 = __expf(s[4 * g + 2] - mnew);
            float p3 = __expf(s[4 * g + 3] - mnew);
            ps += (p0 + p1) + (p2 + p3);
            pw[2 * g + 0] = f2bf(p0) | ((unsigned int)f2bf(p1) << 16);
            pw[2 * g + 1] = f2bf(p2) | ((unsigned int)f2bf(p3) << 16);
        }
        ps += __shfl_xor(ps, 32, 64);
        lrun = lrun * corr + ps;
        mrun = mnew;
        #pragma unroll
        for (int r = 0; r < 16; r++) acc[r] *= corr;

        // P quads -> per-wave LDS: reg group g covers m_local = 8g+4h2+{0..3}
        #pragma unroll
        for (int g = 0; g < 4; g++) {
            *(uint2*)&p_lds[wid][col][8 * g + 4 * h2] = make_uint2(pw[2 * g], pw[2 * g + 1]);
        }

        // PV: out[c][n] += V[c][m16]*P[n][m16], two K=16 chunks
        #pragma unroll
        for (int k = 0; k < 2; k++) {
            bf16x8 vf = *(const bf16x8*)&v_lds[j & 1][col][16 * k + 8 * h2];
            bf16x8 pf = *(const bf16x8*)&p_lds[wid][col][16 * k + 8 * h2];
            acc = __builtin_amdgcn_mfma_f32_32x32x16_bf16(vf, pf, acc, 0, 0, 0);
        }

        // commit next chunk into alternate buffer
        if (j < 31) {
            unsigned int w0 = f2bf(nv.x) | ((unsigned int)f2bf(nv.y) << 16);
            unsigned int w1 = f2bf(nv.z) | ((unsigned int)f2bf(nv.w) << 16);
            *(uint2*)&v_lds[(j + 1) & 1][sc][sm] = make_uint2(w0, w1);
        }
        __syncthreads();
    }

    float inv = 1.f / lrun;
    float* yp = y + ((size_t)(b * 256 + h * 32)) * 1024 + q0 + col;
    #pragma unroll
    for (int r = 0; r < 16; r++) {
        int c = (r & 3) + 8 * (r >> 2) + 4 * h2;
        yp[(size_t)c * 1024] += acc[r] * inv;
    }
}

// ---------------------------------------------------------------------------
extern "C" void kernel_launch(void* const* d_in, const int* in_sizes, int n_in,
                              void* d_out, int out_size, void* d_ws, size_t ws_size,
                              hipStream_t stream)
{
    const float* x      = (const float*)d_in[0];
    const float* w_qkv  = (const float*)d_in[1];
    const float* qkv_g  = (const float*)d_in[2];
    const float* qkv_b  = (const float*)d_in[3];
    const float* qkv_m  = (const float*)d_in[4];
    const float* qkv_v  = (const float*)d_in[5];
    const float* w_pe   = (const float*)d_in[6];
    const float* pe_g   = (const float*)d_in[7];
    const float* pe_b   = (const float*)d_in[8];
    const float* pe_m   = (const float*)d_in[9];
    const float* pe_v   = (const float*)d_in[10];
    const float* w_proj = (const float*)d_in[11];
    const float* proj_g = (const float*)d_in[12];
    const float* proj_b = (const float*)d_in[13];
    const float* proj_m = (const float*)d_in[14];
    const float* proj_v = (const float*)d_in[15];

    float* out = (float*)d_out;
    float* qkv = (float*)d_ws;                               // 16 MB
    float* y   = qkv + (size_t)8 * 512 * 1024;               //  8 MB
    unsigned short* qt = (unsigned short*)(y + (size_t)8 * 256 * 1024);  // 2 MB
    unsigned short* kt = qt + (size_t)64 * 1024 * 16;                     // 2 MB

    // 1) QKV 1x1 conv + BN
    gemm_bn_kernel<512><<<dim3(16, 8, 8), 256, 0, stream>>>(
        x, w_qkv, qkv_g, qkv_b, qkv_m, qkv_v, qkv);

    // 2) Q/K transpose to bf16 fragments (Q pre-scaled by 0.25)
    qk_transpose_kernel<<<dim3(4, 64), 256, 0, stream>>>(qkv, qt, kt);

    // 3) depthwise 3x3 PE conv + BN (writes y)
    pe_conv_bn_kernel<<<dim3(2048), 256, 0, stream>>>(
        qkv, w_pe, pe_g, pe_b, pe_m, pe_v, y);

    // 4) MFMA flash attention (adds into y)
    attn_mfma_kernel<<<dim3(8, 64), 256, 0, stream>>>(qkv, qt, kt, y);

    // 5) proj 1x1 conv + BN -> output
    gemm_bn_kernel<256><<<dim3(16, 4, 8), 256, 0, stream>>>(
        y, w_proj, proj_g, proj_b, proj_m, proj_v, out);
}

// Round 3
// 59.110 us; speedup vs baseline: 8.2146x; 1.6973x over previous
//
#include <hip/hip_runtime.h>
#include <hip/hip_bf16.h>
#include <math.h>

#define EPS 1e-5f

typedef __attribute__((ext_vector_type(8))) short bf16x8;
typedef __attribute__((ext_vector_type(16))) float f32x16;

__device__ inline unsigned short f2bf(float x) {
    __hip_bfloat16 b = __float2bfloat16(x);
    return *reinterpret_cast<unsigned short*>(&b);
}
__device__ inline float bf2f(unsigned short u) {
    unsigned int v = ((unsigned int)u) << 16;
    return __uint_as_float(v);
}

// ---------------------------------------------------------------------------
// MFMA GEMM + BN.  out[b,o,n] = BN_o( sum_c w[o,c] * src[b,c,n] )
// BM=128, BN=64, K=256 in 2 steps of 128. Block = 256 thr = 4 waves (M-split:
// wave wid owns rows [wid*32, wid*32+32) x all 64 n).
// QKV epilogue: o-tile = 2 heads; writes qt/kt bf16 [bh][n][16] (q pre-scaled
// 0.25) and vt bf16 plane [bh][32][1024]. PROJ epilogue: fp32 out.
// ---------------------------------------------------------------------------
template<int CO, bool QKV>
__global__ __launch_bounds__(256)
void gemm_mfma_kernel(const float* __restrict__ src, const float* __restrict__ w,
                      const float* __restrict__ g, const float* __restrict__ bbias,
                      const float* __restrict__ bmean, const float* __restrict__ bvar,
                      float* __restrict__ out,
                      unsigned short* __restrict__ qt,
                      unsigned short* __restrict__ kt,
                      unsigned short* __restrict__ vt)
{
    const int b  = blockIdx.z;
    const int o0 = blockIdx.y * 128;
    const int n0 = blockIdx.x * 64;
    const float* xb = src + (size_t)b * 256 * 1024;

    __shared__ unsigned short As[128][136];  // [o][k], 272B rows (16B-aligned)
    __shared__ unsigned short Bs[64][136];   // [n][k]

    const int tid = threadIdx.x;
    const int wid = tid >> 6;
    const int lane = tid & 63;
    const int col = lane & 31;
    const int h2 = lane >> 5;

    f32x16 acc0 = {}, acc1 = {};

    #pragma unroll
    for (int s = 0; s < 2; s++) {
        const int k0 = s * 128;
        __syncthreads();
        // stage A: 128 o x 128 k fp32 -> bf16
        #pragma unroll
        for (int i = 0; i < 16; i++) {
            int flat = tid + i * 256;
            int row = flat >> 5;
            int kq  = flat & 31;
            float4 a4 = *(const float4*)&w[(size_t)(o0 + row) * 256 + k0 + kq * 4];
            unsigned int w0 = f2bf(a4.x) | ((unsigned int)f2bf(a4.y) << 16);
            unsigned int w1 = f2bf(a4.z) | ((unsigned int)f2bf(a4.w) << 16);
            *(uint2*)&As[row][kq * 4] = make_uint2(w0, w1);
        }
        // stage B transposed: src [c][n] -> Bs [n][k=c]
        #pragma unroll
        for (int i = 0; i < 8; i++) {
            int flat = tid + i * 256;
            int c  = flat >> 4;
            int nq = flat & 15;
            float4 b4 = *(const float4*)&xb[(size_t)(k0 + c) * 1024 + n0 + nq * 4];
            Bs[nq * 4 + 0][c] = f2bf(b4.x);
            Bs[nq * 4 + 1][c] = f2bf(b4.y);
            Bs[nq * 4 + 2][c] = f2bf(b4.z);
            Bs[nq * 4 + 3][c] = f2bf(b4.w);
        }
        __syncthreads();
        #pragma unroll
        for (int ks = 0; ks < 8; ks++) {
            bf16x8 af = *(bf16x8*)&As[wid * 32 + col][ks * 16 + 8 * h2];
            bf16x8 b0 = *(bf16x8*)&Bs[col][ks * 16 + 8 * h2];
            bf16x8 b1 = *(bf16x8*)&Bs[32 + col][ks * 16 + 8 * h2];
            acc0 = __builtin_amdgcn_mfma_f32_32x32x16_bf16(af, b0, acc0, 0, 0, 0);
            acc1 = __builtin_amdgcn_mfma_f32_32x32x16_bf16(af, b1, acc1, 0, 0, 0);
        }
    }

    // epilogue: D row o = o0+wid*32+(r&3)+8*(r>>2)+4*h2, col n = n0+t*32+col
    #pragma unroll
    for (int gq = 0; gq < 4; gq++) {
        const int ob = o0 + wid * 32 + 8 * gq + 4 * h2;
        float4 gg = *(const float4*)&g[ob];
        float4 bb = *(const float4*)&bbias[ob];
        float4 mm = *(const float4*)&bmean[ob];
        float4 vv = *(const float4*)&bvar[ob];
        float sm[4], sa[4];
        sm[0] = gg.x * rsqrtf(vv.x + EPS); sa[0] = bb.x - mm.x * sm[0];
        sm[1] = gg.y * rsqrtf(vv.y + EPS); sa[1] = bb.y - mm.y * sm[1];
        sm[2] = gg.z * rsqrtf(vv.z + EPS); sa[2] = bb.z - mm.z * sm[2];
        sm[3] = gg.w * rsqrtf(vv.w + EPS); sa[3] = bb.w - mm.w * sm[3];

        #pragma unroll
        for (int t = 0; t < 2; t++) {
            const f32x16& ac = t ? acc1 : acc0;
            const int n = n0 + t * 32 + col;
            float val[4];
            #pragma unroll
            for (int j = 0; j < 4; j++) val[j] = ac[4 * gq + j] * sm[j] + sa[j];

            if (!QKV) {
                #pragma unroll
                for (int j = 0; j < 4; j++)
                    out[((size_t)b * CO + ob + j) * 1024 + n] = val[j];
            } else {
                const int h  = blockIdx.y * 2 + (wid >> 1);
                const int bh = b * 8 + h;
                const int rb = 8 * gq + 4 * h2;         // row within 32-row half
                if ((wid & 1) == 0) {
                    // q/k half: rb<16 -> q (scaled), else k
                    const bool isq = (gq < 2);
                    if (isq) {
                        #pragma unroll
                        for (int j = 0; j < 4; j++) val[j] *= 0.25f;
                    }
                    unsigned int w0 = f2bf(val[0]) | ((unsigned int)f2bf(val[1]) << 16);
                    unsigned int w1 = f2bf(val[2]) | ((unsigned int)f2bf(val[3]) << 16);
                    unsigned short* dst = (isq ? qt : kt)
                        + ((size_t)(bh * 1024 + n) * 16 + (rb & 15));
                    *(uint2*)dst = make_uint2(w0, w1);
                } else {
                    // v half: channel = rb + j, plane layout [bh*32+c][m=n]
                    #pragma unroll
                    for (int j = 0; j < 4; j++)
                        vt[(size_t)(bh * 32 + rb + j) * 1024 + n] = f2bf(val[j]);
                }
            }
        }
    }
}

// ---------------------------------------------------------------------------
// Depthwise 3x3 conv + BN on bf16 v planes -> WRITES y (fp32).
// ---------------------------------------------------------------------------
__global__ __launch_bounds__(256)
void pe_conv_bn_kernel(const unsigned short* __restrict__ vt, const float* __restrict__ wpe,
                       const float* __restrict__ g, const float* __restrict__ bbias,
                       const float* __restrict__ bmean, const float* __restrict__ bvar,
                       float* __restrict__ y)
{
    const int bc = blockIdx.x;
    const int b = bc >> 8, ch = bc & 255;
    const unsigned short* vp = vt + (size_t)(b * 256 + ch) * 1024;

    __shared__ float plane[1024];
    const int tid = threadIdx.x;
    {
        ushort4 r4 = *(const ushort4*)&vp[tid * 4];
        float4 f4 = make_float4(bf2f(r4.x), bf2f(r4.y), bf2f(r4.z), bf2f(r4.w));
        *(float4*)&plane[tid * 4] = f4;
    }

    float wk[9];
    #pragma unroll
    for (int i = 0; i < 9; i++) wk[i] = wpe[ch * 9 + i];
    float s  = g[ch] * rsqrtf(bvar[ch] + EPS);
    float sh = bbias[ch] - bmean[ch] * s;
    __syncthreads();

    float* yp = y + ((size_t)b * 256 + ch) * 1024;
    #pragma unroll
    for (int it = 0; it < 4; it++) {
        int p = tid + it * 256;
        int py = p >> 5, px = p & 31;
        float a = 0.f;
        #pragma unroll
        for (int dy = -1; dy <= 1; dy++) {
            int yy = py + dy;
            if (yy < 0 || yy > 31) continue;
            #pragma unroll
            for (int dx = -1; dx <= 1; dx++) {
                int xx = px + dx;
                if (xx < 0 || xx > 31) continue;
                a += plane[yy * 32 + xx] * wk[(dy + 1) * 3 + (dx + 1)];
            }
        }
        yp[p] = a * s + sh;
    }
}

// ---------------------------------------------------------------------------
// Barrier-free MFMA flash attention. 4 waves/block, wave owns 32 queries.
// K/V fragments straight from global (qt/kt/vt, L2-resident); P through
// per-wave LDS only (wave-synchronous). ADDS into y.
// ---------------------------------------------------------------------------
__global__ __launch_bounds__(256)
void attn_mfma_kernel(const unsigned short* __restrict__ qt,
                      const unsigned short* __restrict__ kt,
                      const unsigned short* __restrict__ vt,
                      float* __restrict__ y)
{
    const int bh = blockIdx.y;
    const int b = bh >> 3, h = bh & 7;
    const int tid = threadIdx.x;
    const int wid = tid >> 6;
    const int lane = tid & 63;
    const int col = lane & 31;
    const int h2 = lane >> 5;
    const int q0 = blockIdx.x * 128 + wid * 32;

    __shared__ unsigned short p_lds[4][32][40];

    const bf16x8 qf = *(const bf16x8*)(qt + ((size_t)bh * 1024 + q0 + col) * 16 + h2 * 8);
    const unsigned short* ktb = kt + (size_t)bh * 1024 * 16;
    const unsigned short* vtb = vt + (size_t)bh * 32 * 1024 + (size_t)col * 1024 + 8 * h2;

    f32x16 acc = {};
    float mrun = -1e30f, lrun = 0.f;

    bf16x8 kf  = *(const bf16x8*)(ktb + (size_t)col * 16 + h2 * 8);
    bf16x8 vf0 = *(const bf16x8*)(vtb);
    bf16x8 vf1 = *(const bf16x8*)(vtb + 16);

    for (int j = 0; j < 32; j++) {
        const f32x16 zero = {};
        f32x16 s = __builtin_amdgcn_mfma_f32_32x32x16_bf16(kf, qf, zero, 0, 0, 0);

        // prefetch next chunk's fragments
        bf16x8 kfn, vf0n, vf1n;
        if (j < 31) {
            const int m1 = (j + 1) * 32;
            kfn  = *(const bf16x8*)(ktb + (size_t)(m1 + col) * 16 + h2 * 8);
            vf0n = *(const bf16x8*)(vtb + m1);
            vf1n = *(const bf16x8*)(vtb + m1 + 16);
        }

        // online softmax (lane l + partner l^32 hold query col's 32 scores)
        float tmax = s[0];
        #pragma unroll
        for (int r = 1; r < 16; r++) tmax = fmaxf(tmax, s[r]);
        tmax = fmaxf(tmax, __shfl_xor(tmax, 32, 64));
        float mnew = fmaxf(mrun, tmax);
        float corr = __expf(mrun - mnew);

        float ps = 0.f;
        unsigned int pw[8];
        #pragma unroll
        for (int gq = 0; gq < 4; gq++) {
            float p0 = __expf(s[4 * gq + 0] - mnew);
            float p1 = __expf(s[4 * gq + 1] - mnew);
            float p2 = __expf(s[4 * gq + 2] - mnew);
            float p3 = __expf(s[4 * gq + 3] - mnew);
            ps += (p0 + p1) + (p2 + p3);
            pw[2 * gq + 0] = f2bf(p0) | ((unsigned int)f2bf(p1) << 16);
            pw[2 * gq + 1] = f2bf(p2) | ((unsigned int)f2bf(p3) << 16);
        }
        ps += __shfl_xor(ps, 32, 64);
        lrun = lrun * corr + ps;
        mrun = mnew;
        #pragma unroll
        for (int r = 0; r < 16; r++) acc[r] *= corr;

        // P -> per-wave LDS (reg group gq covers m_local = 8gq+4h2+{0..3})
        #pragma unroll
        for (int gq = 0; gq < 4; gq++)
            *(uint2*)&p_lds[wid][col][8 * gq + 4 * h2] = make_uint2(pw[2 * gq], pw[2 * gq + 1]);

        #pragma unroll
        for (int ks = 0; ks < 2; ks++) {
            bf16x8 pf = *(bf16x8*)&p_lds[wid][col][16 * ks + 8 * h2];
            bf16x8 vf = ks ? vf1 : vf0;
            acc = __builtin_amdgcn_mfma_f32_32x32x16_bf16(vf, pf, acc, 0, 0, 0);
        }

        kf = kfn; vf0 = vf0n; vf1 = vf1n;
    }

    float inv = 1.f / lrun;
    float* yp = y + ((size_t)(b * 256 + h * 32)) * 1024 + q0 + col;
    #pragma unroll
    for (int r = 0; r < 16; r++) {
        int c = (r & 3) + 8 * (r >> 2) + 4 * h2;
        yp[(size_t)c * 1024] += acc[r] * inv;
    }
}

// ---------------------------------------------------------------------------
extern "C" void kernel_launch(void* const* d_in, const int* in_sizes, int n_in,
                              void* d_out, int out_size, void* d_ws, size_t ws_size,
                              hipStream_t stream)
{
    const float* x      = (const float*)d_in[0];
    const float* w_qkv  = (const float*)d_in[1];
    const float* qkv_g  = (const float*)d_in[2];
    const float* qkv_b  = (const float*)d_in[3];
    const float* qkv_m  = (const float*)d_in[4];
    const float* qkv_v  = (const float*)d_in[5];
    const float* w_pe   = (const float*)d_in[6];
    const float* pe_g   = (const float*)d_in[7];
    const float* pe_b   = (const float*)d_in[8];
    const float* pe_m   = (const float*)d_in[9];
    const float* pe_v   = (const float*)d_in[10];
    const float* w_proj = (const float*)d_in[11];
    const float* proj_g = (const float*)d_in[12];
    const float* proj_b = (const float*)d_in[13];
    const float* proj_m = (const float*)d_in[14];
    const float* proj_v = (const float*)d_in[15];

    float* out = (float*)d_out;
    unsigned short* qt = (unsigned short*)d_ws;              // 2 MB
    unsigned short* kt = qt + (size_t)64 * 1024 * 16;        // 2 MB
    unsigned short* vt = kt + (size_t)64 * 1024 * 16;        // 4 MB
    float* y = (float*)(vt + (size_t)64 * 32 * 1024);        // 8 MB

    // 1) QKV GEMM + BN -> qt/kt (bf16 frag layout) + vt (bf16 planes)
    gemm_mfma_kernel<512, true><<<dim3(16, 4, 8), 256, 0, stream>>>(
        x, w_qkv, qkv_g, qkv_b, qkv_m, qkv_v, nullptr, qt, kt, vt);

    // 2) depthwise 3x3 PE conv + BN (writes y)
    pe_conv_bn_kernel<<<dim3(2048), 256, 0, stream>>>(
        vt, w_pe, pe_g, pe_b, pe_m, pe_v, y);

    // 3) barrier-free MFMA flash attention (adds into y)
    attn_mfma_kernel<<<dim3(8, 64), 256, 0, stream>>>(qt, kt, vt, y);

    // 4) proj GEMM + BN -> out
    gemm_mfma_kernel<256, false><<<dim3(16, 2, 8), 256, 0, stream>>>(
        y, w_proj, proj_g, proj_b, proj_m, proj_v, out, nullptr, nullptr, nullptr);
}